// Round 9
// baseline (243.002 us; speedup 1.0000x reference)
//
#include <hip/hip_runtime.h>
#include <hip/hip_bf16.h>
#include <stdint.h>

// Problem constants
#define B_   64
#define T_   300
#define NIN  2312
#define H1   512
#define H2   256
#define NOUT 101
#define KP   2368   // NIN padded to multiple of 64
#define NT   (KP / 64)
#define CH   15     // I1 staging chunk (timesteps); 300 = 20*15
#define NC   (T_ / CH)

typedef __attribute__((ext_vector_type(8))) short bf16x8;
typedef __attribute__((ext_vector_type(4))) float f32x4;
typedef __attribute__((ext_vector_type(8))) unsigned short u16x8;

#define LDS_GLOAD16(g, l) \
  __builtin_amdgcn_global_load_lds((const __attribute__((address_space(1))) void*)(g), \
                                   (__attribute__((address_space(3))) void*)(l), 16, 0, 0)
#define CFENCE() asm volatile("" ::: "memory")

// ---------------- transpose helper ----------------
__global__ void transpose_k(const float* __restrict__ src, float* __restrict__ dst,
                            int R, int C) {
    int idx = blockIdx.x * 256 + threadIdx.x;
    if (idx < R * C) {
        int r = idx / C, c = idx % C;
        dst[c * R + r] = src[r * C + c];
    }
}

// ---------------- fp32 -> bf16 (RNE) with K-padding (W only) ----------------
__device__ __forceinline__ unsigned short rne_bf16(float v) {
    union { float f; unsigned u; } cv; cv.f = v;
    return (unsigned short)((cv.u + 0x7fff + ((cv.u >> 16) & 1)) >> 16);
}

__global__ __launch_bounds__(256) void cvt_pad_bf16(const float* __restrict__ src,
                                                    unsigned short* __restrict__ dst,
                                                    int R, int C, int Cp) {
    int idx = blockIdx.x * 256 + threadIdx.x;
    int cpw = Cp >> 3;
    if (idx >= R * cpw) return;
    int row = idx / cpw;
    int c0 = (idx - row * cpw) << 3;
    u16x8 o;
#pragma unroll
    for (int j = 0; j < 8; ++j) {
        int k = c0 + j;
        o[j] = (k < C) ? rne_bf16(src[(size_t)row * C + k]) : (unsigned short)0;
    }
    *(u16x8*)(dst + (size_t)row * Cp + c0) = o;
}

// ---------------- bf16 MFMA GEMM: fused A-cvt, swizzled LDS, 2-phase dbuf ------
// Y[M][H1] = bf16(X[M][NIN]) * Wb[H1][KP]^T
// LDS swizzle: LDS[row][cb] holds global[row][cb ^ 16*(row&7)] (bytes) on both
// operands; reads use col ^ ((row&7)<<3) elements -> 2-way conflicts (free).
// Pipeline (m248 2-phase): issue A(kt+1)->regs then B(kt+1)->gload_lds BEFORE
// MFMA(cur); after MFMA: vmcnt(4) [A ready, B in flight], cvt+ds_write A(nxt),
// vmcnt(0)+lgkmcnt(0)+barrier once per kt. Load latency hides under compute.
__device__ __forceinline__ unsigned pack2bf(float lo, float hi) {
    return ((unsigned)rne_bf16(hi) << 16) | rne_bf16(lo);
}

__global__ __launch_bounds__(256) void gemm_bf16_fa(
    const float* __restrict__ X,             // [M][NIN] fp32
    const unsigned short* __restrict__ Wb,   // [H1][KP] bf16 bits
    float* __restrict__ Y)                   // [M][H1]
{
    __shared__ __align__(16) unsigned short As[2][128][64];   // 32 KB
    __shared__ __align__(16) unsigned short Bs[2][128][64];   // 32 KB

    const int tid  = threadIdx.x;
    const int wave = tid >> 6, lane = tid & 63;
    const int wr = wave >> 1, wc = wave & 1;          // 2x2 waves, 64x64 each

    // XCD-bijective swizzle: 600 blocks, 600 % 8 == 0.
    const int d  = blockIdx.x + gridDim.x * blockIdx.y;   // 0..599
    const int wg = (d & 7) * 75 + (d >> 3);
    const int bn = wg & 3, bm = wg >> 2;
    const int m0 = bm * 128, n0 = bn * 128;
    const int fr = lane & 15, fq = lane >> 4;
    const int swz = (fr & 7) << 3;                    // element XOR for reads

    f32x4 acc[4][4] = {};

    // ---- A addressing (fp32 source; reg-staged; swizzled ds_write dest) ----
    const int arl  = lane >> 3;                       // row-sub 0..7
    const int acol = 8 * (lane & 7);                  // source col (elements)
    const float* gAf = X + (size_t)(m0 + 32 * wave + arl) * NIN + acol;
    const int adstc = 8 * ((lane & 7) ^ (arl & 7));   // swizzled dest col

    // ---- B addressing (bf16 source; pre-swizzled per-lane source col) ----
    const size_t rowBW = (size_t)KP * 2;
    const int bcolsw = 16 * ((lane & 7) ^ ((lane >> 3) & 7));   // bytes
    const char* gB = (const char*)Wb + (size_t)(n0 + 32 * wave + (lane >> 3)) * rowBW + bcolsw;

    float4 fa[4], fb[4];
    auto loadA = [&](int kt) {
        const int kc = kt * 64;
#pragma unroll
        for (int s = 0; s < 4; ++s) {
            if (kc + acol < NIN) {   // NIN%8==0: float4 pair fully valid or pad
                const float4* p = (const float4*)(gAf + (size_t)s * 8 * NIN + kc);
                fa[s] = p[0]; fb[s] = p[1];
            } else {
                fa[s] = make_float4(0.f, 0.f, 0.f, 0.f);
                fb[s] = make_float4(0.f, 0.f, 0.f, 0.f);
            }
        }
    };
    auto stageB = [&](int kt, int bufi) {
        const size_t ko = (size_t)kt * 128;
        unsigned short* lB = &Bs[bufi][32 * wave][0];
#pragma unroll
        for (int s = 0; s < 4; ++s)
            LDS_GLOAD16(gB + ko + (size_t)s * 8 * rowBW, lB + s * 8 * 64);
    };
    auto writeA = [&](int bufi) {
        unsigned short* dst = &As[bufi][32 * wave + arl][adstc];
#pragma unroll
        for (int s = 0; s < 4; ++s) {
            uint4 o;
            o.x = pack2bf(fa[s].x, fa[s].y);
            o.y = pack2bf(fa[s].z, fa[s].w);
            o.z = pack2bf(fb[s].x, fb[s].y);
            o.w = pack2bf(fb[s].z, fb[s].w);
            *(uint4*)(dst + (size_t)s * 8 * 64) = o;
        }
    };

    // ---- prologue: fill buffer 0 ----
    loadA(0);
    CFENCE();
    stageB(0, 0);
    CFENCE();
    writeA(0);                 // compiler inserts the vmcnt wait for fa/fb
    CFENCE();
    asm volatile("s_waitcnt vmcnt(0) lgkmcnt(0)" ::: "memory");
    __builtin_amdgcn_s_barrier();

    for (int kt = 0; kt < NT; ++kt) {
        const int cur = kt & 1, nxt = cur ^ 1;
        const bool more = (kt + 1 < NT);

        // ---- issue next tile's loads (stay in flight across MFMA) ----
        if (more) {
            loadA(kt + 1);         // vmem: A x8 (oldest)
            CFENCE();
            stageB(kt + 1, nxt);   // vmem: +B x4
            CFENCE();
        }

        // ---- MFMA on buffer cur ----
#pragma unroll
        for (int ks = 0; ks < 2; ++ks) {
            bf16x8 a[4], b[4];
#pragma unroll
            for (int mi = 0; mi < 4; ++mi)
                a[mi] = *(const bf16x8*)&As[cur][wr * 64 + mi * 16 + fr][(ks * 32 + fq * 8) ^ swz];
#pragma unroll
            for (int nj = 0; nj < 4; ++nj)
                b[nj] = *(const bf16x8*)&Bs[cur][wc * 64 + nj * 16 + fr][(ks * 32 + fq * 8) ^ swz];
#pragma unroll
            for (int mi = 0; mi < 4; ++mi)
#pragma unroll
                for (int nj = 0; nj < 4; ++nj)
                    acc[mi][nj] = __builtin_amdgcn_mfma_f32_16x16x32_bf16(
                        a[mi], b[nj], acc[mi][nj], 0, 0, 0);
        }

        if (more) {
            CFENCE();
            asm volatile("s_waitcnt vmcnt(4)" ::: "memory");   // A regs landed; B in flight
            writeA(nxt);
            CFENCE();
            // all staging visible + this buffer's ds_reads drained, then sync
            asm volatile("s_waitcnt vmcnt(0) lgkmcnt(0)" ::: "memory");
            __builtin_amdgcn_s_barrier();
        }
    }

    // C/D layout (m89-verified): col = lane&15, row = (lane>>4)*4 + reg
#pragma unroll
    for (int mi = 0; mi < 4; ++mi)
#pragma unroll
        for (int nj = 0; nj < 4; ++nj) {
            int r0 = m0 + wr * 64 + mi * 16 + fq * 4;
            int c  = n0 + wc * 64 + nj * 16 + fr;
#pragma unroll
            for (int r = 0; r < 4; ++r)
                Y[(size_t)(r0 + r) * H1 + c] = acc[mi][nj][r];
        }
}

// ---------------- wave-per-batch SNN scan (v6, unchanged) ----------------
__global__ __launch_bounds__(64) void snn_scan_wave(
    const float* __restrict__ I1ff,   // [B][T][H1]
    const float* __restrict__ wrt,    // [H1][H1]  wrt[i][h] = w_rec[h][i]
    const float* __restrict__ w2t,    // [H1][H2]  w2t[i][g] = w2[g][i]
    const float* __restrict__ w3t,    // [H2][NOUT]
    const float* __restrict__ alpha1, const float* __restrict__ rho1,
    const float* __restrict__ beta_a1,
    const float* __restrict__ alpha2, const float* __restrict__ rho2,
    const float* __restrict__ beta_a2,
    const float* __restrict__ beta_out,
    float* __restrict__ out)          // [B][NOUT]
{
    __shared__ __align__(16) float Ich[2][CH][H1];   // 60 KB

    const int b = blockIdx.x;
    const int lane = threadIdx.x;     // 0..63

    float v1[8], a1[8], s1f[8], al1[8], oml1[8], rh1[8], ba1[8];
#pragma unroll
    for (int j = 0; j < 8; ++j) {
        int h = lane + 64 * j;
        v1[j] = 0.f; a1[j] = 0.f; s1f[j] = 0.f;
        al1[j] = alpha1[h]; oml1[j] = 1.f - al1[j];
        rh1[j] = rho1[h];   ba1[j] = beta_a1[h];
    }
    float v2[4], a2[4], s2f[4], al2[4], oml2[4], rh2[4], ba2[4];
#pragma unroll
    for (int j = 0; j < 4; ++j) {
        int h = lane + 64 * j;
        v2[j] = 0.f; a2[j] = 0.f; s2f[j] = 0.f;
        al2[j] = alpha2[h]; oml2[j] = 1.f - al2[j];
        rh2[j] = rho2[h];   ba2[j] = beta_a2[h];
    }
    float vo0 = 0.f, vo1 = 0.f, vs0 = 0.f, vs1 = 0.f;
    const float bo0 = beta_out[lane];
    const float ombo0 = 1.f - bo0;
    const float bo1 = (lane < NOUT - 64) ? beta_out[64 + lane] : 0.f;
    const float ombo1 = 1.f - bo1;

    unsigned long long M1[8];
#pragma unroll
    for (int j = 0; j < 8; ++j) M1[j] = 0ull;
    bool prev1 = false;

    const float* I1p = I1ff + (size_t)b * T_ * H1;

    auto stage = [&](int c, int bufi) {
        const float* src = I1p + (size_t)c * CH * H1 + lane * 4;
#pragma unroll
        for (int s = 0; s < CH; ++s) {
            LDS_GLOAD16(src + (size_t)s * H1,       &Ich[bufi][s][0]);
            LDS_GLOAD16(src + (size_t)s * H1 + 256, &Ich[bufi][s][256]);
        }
    };

    stage(0, 0);

    for (int c = 0; c < NC; ++c) {
        const int buf = c & 1;
        asm volatile("s_waitcnt vmcnt(0)" ::: "memory");

        float cur[8];
#pragma unroll
        for (int j = 0; j < 8; ++j) cur[j] = Ich[buf][0][lane + 64 * j];

        for (int s = 0; s < CH; ++s) {
            float nxt[8];
            if (s + 1 < CH) {
#pragma unroll
                for (int j = 0; j < 8; ++j) nxt[j] = Ich[buf][s + 1][lane + 64 * j];
            }

            float rec[8] = {0.f,0.f,0.f,0.f,0.f,0.f,0.f,0.f};
            if (prev1) {
#pragma unroll
                for (int w = 0; w < 8; ++w) {
                    unsigned long long bits = M1[w];
                    while (bits) {
                        int p = __builtin_ctzll(bits);
                        bits &= bits - 1;
                        int i = (w << 6) + p;
                        const float* r = wrt + (size_t)i * H1 + lane;
#pragma unroll
                        for (int j = 0; j < 8; ++j) rec[j] += r[64 * j];
                    }
                }
            }

            unsigned m = 0;
#pragma unroll
            for (int j = 0; j < 8; ++j) {
                float I1v = cur[j] + rec[j];
                float v1n = fmaf(al1[j], v1[j], oml1[j] * (I1v - a1[j]));
                bool  sp  = v1n > 1.f;
                v1[j] = sp ? v1n - 1.f : v1n;
                a1[j] = fmaf(rh1[j], a1[j], ba1[j] * s1f[j]);
                s1f[j] = sp ? 1.f : 0.f;
                m |= (sp ? 1u : 0u) << j;
            }

            unsigned long long anyb = __ballot(m != 0);
            float I2[4] = {0.f, 0.f, 0.f, 0.f};
            if (anyb) {
                prev1 = true;
#pragma unroll
                for (int j = 0; j < 8; ++j) M1[j] = __ballot((m >> j) & 1);
#pragma unroll
                for (int w = 0; w < 8; ++w) {
                    unsigned long long bits = M1[w];
                    while (bits) {
                        int p = __builtin_ctzll(bits);
                        bits &= bits - 1;
                        int i = (w << 6) + p;
                        const float* r = w2t + (size_t)i * H2 + lane;
#pragma unroll
                        for (int j = 0; j < 4; ++j) I2[j] += r[64 * j];
                    }
                }
            } else {
                prev1 = false;
            }

            unsigned m2 = 0;
#pragma unroll
            for (int j = 0; j < 4; ++j) {
                float v2n = fmaf(al2[j], v2[j], oml2[j] * (I2[j] - a2[j]));
                bool  sp  = v2n > 1.f;
                v2[j] = sp ? v2n - 1.f : v2n;
                a2[j] = fmaf(rh2[j], a2[j], ba2[j] * s2f[j]);
                s2f[j] = sp ? 1.f : 0.f;
                m2 |= (sp ? 1u : 0u) << j;
            }

            unsigned long long any2 = __ballot(m2 != 0);
            float io0 = 0.f, io1 = 0.f;
            if (any2) {
#pragma unroll
                for (int w = 0; w < 4; ++w) {
                    unsigned long long bits = __ballot((m2 >> w) & 1);
                    while (bits) {
                        int p = __builtin_ctzll(bits);
                        bits &= bits - 1;
                        int i = (w << 6) + p;
                        io0 += w3t[(size_t)i * NOUT + lane];
                        if (lane < NOUT - 64) io1 += w3t[(size_t)i * NOUT + 64 + lane];
                    }
                }
            }
            vo0 = fmaf(bo0, vo0, ombo0 * io0);
            vo1 = fmaf(bo1, vo1, ombo1 * io1);
            vs0 += vo0;
            vs1 += vo1;

#pragma unroll
            for (int j = 0; j < 8; ++j) cur[j] = nxt[j];
        }

        if (c + 1 < NC) stage(c + 1, buf ^ 1);
    }

    out[b * NOUT + lane] = vs0 * (1.f / (float)T_);
    if (lane < NOUT - 64) out[b * NOUT + 64 + lane] = vs1 * (1.f / (float)T_);
}

// ---------------- launch ----------------
extern "C" void kernel_launch(void* const* d_in, const int* in_sizes, int n_in,
                              void* d_out, int out_size, void* d_ws, size_t ws_size,
                              hipStream_t stream) {
    const float* x      = (const float*)d_in[0];   // [B][T][NIN]
    const float* w1     = (const float*)d_in[1];   // [H1][NIN]
    const float* w_rec  = (const float*)d_in[2];   // [H1][H1]
    const float* w2     = (const float*)d_in[3];   // [H2][H1]
    const float* w3     = (const float*)d_in[4];   // [NOUT][H2]
    const float* alpha1 = (const float*)d_in[5];
    const float* rho1   = (const float*)d_in[6];
    const float* beta_a1= (const float*)d_in[7];
    const float* alpha2 = (const float*)d_in[8];
    const float* rho2   = (const float*)d_in[9];
    const float* beta_a2= (const float*)d_in[10];
    const float* beta_out=(const float*)d_in[11];
    float* out = (float*)d_out;

    const int M = B_ * T_;                         // 19200

    size_t off = 0;
    auto take = [&](size_t bytes) {
        void* p = (char*)d_ws + off;
        off += (bytes + 255) & ~(size_t)255;
        return p;
    };
    float* I1ff = (float*)take((size_t)M * H1 * 4);            // 39.3 MB
    float* wrt  = (float*)take((size_t)H1 * H1 * 4);
    float* w2t  = (float*)take((size_t)H1 * H2 * 4);
    float* w3t  = (float*)take((size_t)H2 * NOUT * 4);
    unsigned short* w1b = (unsigned short*)take((size_t)H1 * KP * 2);  // 2.4 MB

    transpose_k<<<(H1 * H1 + 255) / 256, 256, 0, stream>>>(w_rec, wrt, H1, H1);
    transpose_k<<<(H2 * H1 + 255) / 256, 256, 0, stream>>>(w2, w2t, H2, H1);
    transpose_k<<<(NOUT * H2 + 255) / 256, 256, 0, stream>>>(w3, w3t, NOUT, H2);

    // W -> bf16 (tiny); A converts in-GEMM
    int nw = H1 * (KP / 8);
    cvt_pad_bf16<<<(nw + 255) / 256, 256, 0, stream>>>(w1, w1b, H1, NIN, KP);

    dim3 gg(H1 / 128, M / 128);   // (4, 150) = 600 blocks (swizzle assumes 600)
    gemm_bf16_fa<<<gg, 256, 0, stream>>>(x, w1b, I1ff);

    snn_scan_wave<<<B_, 64, 0, stream>>>(I1ff, wrt, w2t, w3t,
                                         alpha1, rho1, beta_a1,
                                         alpha2, rho2, beta_a2,
                                         beta_out, out);
}

// Round 10
// 228.365 us; speedup vs baseline: 1.0641x; 1.0641x over previous
//
#include <hip/hip_runtime.h>
#include <hip/hip_bf16.h>
#include <stdint.h>

// Problem constants
#define B_   64
#define T_   300
#define NIN  2312
#define H1   512
#define H2   256
#define NOUT 101
#define KP   2368   // NIN padded to multiple of 64
#define NT   (KP / 64)
#define CH   15     // I1 staging chunk (timesteps); 300 = 20*15
#define NC   (T_ / CH)

typedef __attribute__((ext_vector_type(8))) short bf16x8;
typedef __attribute__((ext_vector_type(4))) float f32x4;
typedef __attribute__((ext_vector_type(8))) unsigned short u16x8;

#define LDS_GLOAD16(g, l) \
  __builtin_amdgcn_global_load_lds((const __attribute__((address_space(1))) void*)(g), \
                                   (__attribute__((address_space(3))) void*)(l), 16, 0, 0)
#define CFENCE() asm volatile("" ::: "memory")

// ---------------- transpose helper ----------------
__global__ void transpose_k(const float* __restrict__ src, float* __restrict__ dst,
                            int R, int C) {
    int idx = blockIdx.x * 256 + threadIdx.x;
    if (idx < R * C) {
        int r = idx / C, c = idx % C;
        dst[c * R + r] = src[r * C + c];
    }
}

// ---------------- fp32 -> bf16 (RNE) with K-padding (W only) ----------------
__device__ __forceinline__ unsigned short rne_bf16(float v) {
    union { float f; unsigned u; } cv; cv.f = v;
    return (unsigned short)((cv.u + 0x7fff + ((cv.u >> 16) & 1)) >> 16);
}

__global__ __launch_bounds__(256) void cvt_pad_bf16(const float* __restrict__ src,
                                                    unsigned short* __restrict__ dst,
                                                    int R, int C, int Cp) {
    int idx = blockIdx.x * 256 + threadIdx.x;
    int cpw = Cp >> 3;
    if (idx >= R * cpw) return;
    int row = idx / cpw;
    int c0 = (idx - row * cpw) << 3;
    u16x8 o;
#pragma unroll
    for (int j = 0; j < 8; ++j) {
        int k = c0 + j;
        o[j] = (k < C) ? rne_bf16(src[(size_t)row * C + k]) : (unsigned short)0;
    }
    *(u16x8*)(dst + (size_t)row * Cp + c0) = o;
}

// ------ bf16 MFMA GEMM: fused A-cvt, swizzled LDS, B-only double buffer ------
// Y[M][H1] = bf16(X[M][NIN]) * Wb[H1][KP]^T
// LDS swizzle: LDS[row][cb] holds global[row][cb ^ 16*(row&7)] (bytes) on both
// operands; reads use col ^ ((row&7)<<3) elements -> 2-way conflicts (free).
// Pipeline: per kt, issue loadA(kt+1)->regs (8 vmem) + stageB(kt+1)->Bs[nxt]
// (4 vmem) BEFORE the MFMA phase; after MFMA: barrier (reads done), vmcnt(4)
// [A landed, B in flight], writeA, vmcnt(0)+lgkmcnt(0)+barrier. B gets a full
// MFMA phase of flight; As stays single-buffered so LDS = 48 KB (3 blocks/CU).
__device__ __forceinline__ unsigned pack2bf(float lo, float hi) {
    return ((unsigned)rne_bf16(hi) << 16) | rne_bf16(lo);
}

__global__ __launch_bounds__(256) void gemm_bf16_fa(
    const float* __restrict__ X,             // [M][NIN] fp32
    const unsigned short* __restrict__ Wb,   // [H1][KP] bf16 bits
    float* __restrict__ Y)                   // [M][H1]
{
    __shared__ __align__(16) unsigned short As[128][64];      // 16 KB
    __shared__ __align__(16) unsigned short Bs[2][128][64];   // 32 KB

    const int tid  = threadIdx.x;
    const int wave = tid >> 6, lane = tid & 63;
    const int wr = wave >> 1, wc = wave & 1;          // 2x2 waves, 64x64 each

    // XCD-bijective swizzle: 600 blocks, 600 % 8 == 0.
    const int d  = blockIdx.x + gridDim.x * blockIdx.y;   // 0..599
    const int wg = (d & 7) * 75 + (d >> 3);
    const int bn = wg & 3, bm = wg >> 2;
    const int m0 = bm * 128, n0 = bn * 128;
    const int fr = lane & 15, fq = lane >> 4;
    const int swz = (fr & 7) << 3;                    // element XOR for reads

    f32x4 acc[4][4] = {};

    // ---- A addressing (fp32 source; reg-staged; swizzled ds_write dest) ----
    const int arl  = lane >> 3;                       // row-sub 0..7
    const int acol = 8 * (lane & 7);                  // source col (elements)
    const float* gAf = X + (size_t)(m0 + 32 * wave + arl) * NIN + acol;
    const int adstc = 8 * ((lane & 7) ^ (arl & 7));   // swizzled dest col

    // ---- B addressing (bf16 source; pre-swizzled per-lane source col) ----
    const size_t rowBW = (size_t)KP * 2;
    const int bcolsw = 16 * ((lane & 7) ^ ((lane >> 3) & 7));   // bytes
    const char* gB = (const char*)Wb + (size_t)(n0 + 32 * wave + (lane >> 3)) * rowBW + bcolsw;

    float4 fa[4], fb[4];
    auto loadA = [&](int kt) {
        const int kc = kt * 64;
#pragma unroll
        for (int s = 0; s < 4; ++s) {
            if (kc + acol < NIN) {   // NIN%8==0: float4 pair fully valid or pad
                const float4* p = (const float4*)(gAf + (size_t)s * 8 * NIN + kc);
                fa[s] = p[0]; fb[s] = p[1];
            } else {
                fa[s] = make_float4(0.f, 0.f, 0.f, 0.f);
                fb[s] = make_float4(0.f, 0.f, 0.f, 0.f);
            }
        }
    };
    auto stageB = [&](int kt, int bufi) {
        const size_t ko = (size_t)kt * 128;
        unsigned short* lB = &Bs[bufi][32 * wave][0];
#pragma unroll
        for (int s = 0; s < 4; ++s)
            LDS_GLOAD16(gB + ko + (size_t)s * 8 * rowBW, lB + s * 8 * 64);
    };
    auto writeA = [&]() {
        unsigned short* dst = &As[32 * wave + arl][adstc];
#pragma unroll
        for (int s = 0; s < 4; ++s) {
            uint4 o;
            o.x = pack2bf(fa[s].x, fa[s].y);
            o.y = pack2bf(fa[s].z, fa[s].w);
            o.z = pack2bf(fb[s].x, fb[s].y);
            o.w = pack2bf(fb[s].z, fb[s].w);
            *(uint4*)(dst + (size_t)s * 8 * 64) = o;
        }
    };

    // ---- prologue: fill As(0) and Bs[0] ----
    loadA(0);
    CFENCE();
    stageB(0, 0);
    CFENCE();
    writeA();                  // compiler inserts the vmcnt wait for fa/fb
    CFENCE();
    asm volatile("s_waitcnt vmcnt(0) lgkmcnt(0)" ::: "memory");
    __builtin_amdgcn_s_barrier();

    for (int kt = 0; kt < NT; ++kt) {
        const int cur = kt & 1, nxt = cur ^ 1;
        const bool more = (kt + 1 < NT);

        // ---- issue next tile's loads (stay in flight across MFMA) ----
        if (more) {
            loadA(kt + 1);         // vmem: A x8 (oldest)
            CFENCE();
            stageB(kt + 1, nxt);   // vmem: +B x4
            CFENCE();
        }

        // ---- MFMA on As / Bs[cur] ----
#pragma unroll
        for (int ks = 0; ks < 2; ++ks) {
            bf16x8 a[4], b[4];
#pragma unroll
            for (int mi = 0; mi < 4; ++mi)
                a[mi] = *(const bf16x8*)&As[wr * 64 + mi * 16 + fr][(ks * 32 + fq * 8) ^ swz];
#pragma unroll
            for (int nj = 0; nj < 4; ++nj)
                b[nj] = *(const bf16x8*)&Bs[cur][wc * 64 + nj * 16 + fr][(ks * 32 + fq * 8) ^ swz];
#pragma unroll
            for (int mi = 0; mi < 4; ++mi)
#pragma unroll
                for (int nj = 0; nj < 4; ++nj)
                    acc[mi][nj] = __builtin_amdgcn_mfma_f32_16x16x32_bf16(
                        a[mi], b[nj], acc[mi][nj], 0, 0, 0);
        }

        if (more) {
            CFENCE();
            __builtin_amdgcn_s_barrier();   // all waves done reading As/Bs[cur]
            asm volatile("s_waitcnt vmcnt(4)" ::: "memory");   // A landed; B in flight
            writeA();
            CFENCE();
            // B(kt+1) landed + As write visible, then sync
            asm volatile("s_waitcnt vmcnt(0) lgkmcnt(0)" ::: "memory");
            __builtin_amdgcn_s_barrier();
        }
    }

    // C/D layout (m89-verified): col = lane&15, row = (lane>>4)*4 + reg
#pragma unroll
    for (int mi = 0; mi < 4; ++mi)
#pragma unroll
        for (int nj = 0; nj < 4; ++nj) {
            int r0 = m0 + wr * 64 + mi * 16 + fq * 4;
            int c  = n0 + wc * 64 + nj * 16 + fr;
#pragma unroll
            for (int r = 0; r < 4; ++r)
                Y[(size_t)(r0 + r) * H1 + c] = acc[mi][nj][r];
        }
}

// ---------------- wave-per-batch SNN scan (v6, unchanged) ----------------
__global__ __launch_bounds__(64) void snn_scan_wave(
    const float* __restrict__ I1ff,   // [B][T][H1]
    const float* __restrict__ wrt,    // [H1][H1]  wrt[i][h] = w_rec[h][i]
    const float* __restrict__ w2t,    // [H1][H2]  w2t[i][g] = w2[g][i]
    const float* __restrict__ w3t,    // [H2][NOUT]
    const float* __restrict__ alpha1, const float* __restrict__ rho1,
    const float* __restrict__ beta_a1,
    const float* __restrict__ alpha2, const float* __restrict__ rho2,
    const float* __restrict__ beta_a2,
    const float* __restrict__ beta_out,
    float* __restrict__ out)          // [B][NOUT]
{
    __shared__ __align__(16) float Ich[2][CH][H1];   // 60 KB

    const int b = blockIdx.x;
    const int lane = threadIdx.x;     // 0..63

    float v1[8], a1[8], s1f[8], al1[8], oml1[8], rh1[8], ba1[8];
#pragma unroll
    for (int j = 0; j < 8; ++j) {
        int h = lane + 64 * j;
        v1[j] = 0.f; a1[j] = 0.f; s1f[j] = 0.f;
        al1[j] = alpha1[h]; oml1[j] = 1.f - al1[j];
        rh1[j] = rho1[h];   ba1[j] = beta_a1[h];
    }
    float v2[4], a2[4], s2f[4], al2[4], oml2[4], rh2[4], ba2[4];
#pragma unroll
    for (int j = 0; j < 4; ++j) {
        int h = lane + 64 * j;
        v2[j] = 0.f; a2[j] = 0.f; s2f[j] = 0.f;
        al2[j] = alpha2[h]; oml2[j] = 1.f - al2[j];
        rh2[j] = rho2[h];   ba2[j] = beta_a2[h];
    }
    float vo0 = 0.f, vo1 = 0.f, vs0 = 0.f, vs1 = 0.f;
    const float bo0 = beta_out[lane];
    const float ombo0 = 1.f - bo0;
    const float bo1 = (lane < NOUT - 64) ? beta_out[64 + lane] : 0.f;
    const float ombo1 = 1.f - bo1;

    unsigned long long M1[8];
#pragma unroll
    for (int j = 0; j < 8; ++j) M1[j] = 0ull;
    bool prev1 = false;

    const float* I1p = I1ff + (size_t)b * T_ * H1;

    auto stage = [&](int c, int bufi) {
        const float* src = I1p + (size_t)c * CH * H1 + lane * 4;
#pragma unroll
        for (int s = 0; s < CH; ++s) {
            LDS_GLOAD16(src + (size_t)s * H1,       &Ich[bufi][s][0]);
            LDS_GLOAD16(src + (size_t)s * H1 + 256, &Ich[bufi][s][256]);
        }
    };

    stage(0, 0);

    for (int c = 0; c < NC; ++c) {
        const int buf = c & 1;
        asm volatile("s_waitcnt vmcnt(0)" ::: "memory");

        float cur[8];
#pragma unroll
        for (int j = 0; j < 8; ++j) cur[j] = Ich[buf][0][lane + 64 * j];

        for (int s = 0; s < CH; ++s) {
            float nxt[8];
            if (s + 1 < CH) {
#pragma unroll
                for (int j = 0; j < 8; ++j) nxt[j] = Ich[buf][s + 1][lane + 64 * j];
            }

            float rec[8] = {0.f,0.f,0.f,0.f,0.f,0.f,0.f,0.f};
            if (prev1) {
#pragma unroll
                for (int w = 0; w < 8; ++w) {
                    unsigned long long bits = M1[w];
                    while (bits) {
                        int p = __builtin_ctzll(bits);
                        bits &= bits - 1;
                        int i = (w << 6) + p;
                        const float* r = wrt + (size_t)i * H1 + lane;
#pragma unroll
                        for (int j = 0; j < 8; ++j) rec[j] += r[64 * j];
                    }
                }
            }

            unsigned m = 0;
#pragma unroll
            for (int j = 0; j < 8; ++j) {
                float I1v = cur[j] + rec[j];
                float v1n = fmaf(al1[j], v1[j], oml1[j] * (I1v - a1[j]));
                bool  sp  = v1n > 1.f;
                v1[j] = sp ? v1n - 1.f : v1n;
                a1[j] = fmaf(rh1[j], a1[j], ba1[j] * s1f[j]);
                s1f[j] = sp ? 1.f : 0.f;
                m |= (sp ? 1u : 0u) << j;
            }

            unsigned long long anyb = __ballot(m != 0);
            float I2[4] = {0.f, 0.f, 0.f, 0.f};
            if (anyb) {
                prev1 = true;
#pragma unroll
                for (int j = 0; j < 8; ++j) M1[j] = __ballot((m >> j) & 1);
#pragma unroll
                for (int w = 0; w < 8; ++w) {
                    unsigned long long bits = M1[w];
                    while (bits) {
                        int p = __builtin_ctzll(bits);
                        bits &= bits - 1;
                        int i = (w << 6) + p;
                        const float* r = w2t + (size_t)i * H2 + lane;
#pragma unroll
                        for (int j = 0; j < 4; ++j) I2[j] += r[64 * j];
                    }
                }
            } else {
                prev1 = false;
            }

            unsigned m2 = 0;
#pragma unroll
            for (int j = 0; j < 4; ++j) {
                float v2n = fmaf(al2[j], v2[j], oml2[j] * (I2[j] - a2[j]));
                bool  sp  = v2n > 1.f;
                v2[j] = sp ? v2n - 1.f : v2n;
                a2[j] = fmaf(rh2[j], a2[j], ba2[j] * s2f[j]);
                s2f[j] = sp ? 1.f : 0.f;
                m2 |= (sp ? 1u : 0u) << j;
            }

            unsigned long long any2 = __ballot(m2 != 0);
            float io0 = 0.f, io1 = 0.f;
            if (any2) {
#pragma unroll
                for (int w = 0; w < 4; ++w) {
                    unsigned long long bits = __ballot((m2 >> w) & 1);
                    while (bits) {
                        int p = __builtin_ctzll(bits);
                        bits &= bits - 1;
                        int i = (w << 6) + p;
                        io0 += w3t[(size_t)i * NOUT + lane];
                        if (lane < NOUT - 64) io1 += w3t[(size_t)i * NOUT + 64 + lane];
                    }
                }
            }
            vo0 = fmaf(bo0, vo0, ombo0 * io0);
            vo1 = fmaf(bo1, vo1, ombo1 * io1);
            vs0 += vo0;
            vs1 += vo1;

#pragma unroll
            for (int j = 0; j < 8; ++j) cur[j] = nxt[j];
        }

        if (c + 1 < NC) stage(c + 1, buf ^ 1);
    }

    out[b * NOUT + lane] = vs0 * (1.f / (float)T_);
    if (lane < NOUT - 64) out[b * NOUT + 64 + lane] = vs1 * (1.f / (float)T_);
}

// ---------------- launch ----------------
extern "C" void kernel_launch(void* const* d_in, const int* in_sizes, int n_in,
                              void* d_out, int out_size, void* d_ws, size_t ws_size,
                              hipStream_t stream) {
    const float* x      = (const float*)d_in[0];   // [B][T][NIN]
    const float* w1     = (const float*)d_in[1];   // [H1][NIN]
    const float* w_rec  = (const float*)d_in[2];   // [H1][H1]
    const float* w2     = (const float*)d_in[3];   // [H2][H1]
    const float* w3     = (const float*)d_in[4];   // [NOUT][H2]
    const float* alpha1 = (const float*)d_in[5];
    const float* rho1   = (const float*)d_in[6];
    const float* beta_a1= (const float*)d_in[7];
    const float* alpha2 = (const float*)d_in[8];
    const float* rho2   = (const float*)d_in[9];
    const float* beta_a2= (const float*)d_in[10];
    const float* beta_out=(const float*)d_in[11];
    float* out = (float*)d_out;

    const int M = B_ * T_;                         // 19200

    size_t off = 0;
    auto take = [&](size_t bytes) {
        void* p = (char*)d_ws + off;
        off += (bytes + 255) & ~(size_t)255;
        return p;
    };
    float* I1ff = (float*)take((size_t)M * H1 * 4);            // 39.3 MB
    float* wrt  = (float*)take((size_t)H1 * H1 * 4);
    float* w2t  = (float*)take((size_t)H1 * H2 * 4);
    float* w3t  = (float*)take((size_t)H2 * NOUT * 4);
    unsigned short* w1b = (unsigned short*)take((size_t)H1 * KP * 2);  // 2.4 MB

    transpose_k<<<(H1 * H1 + 255) / 256, 256, 0, stream>>>(w_rec, wrt, H1, H1);
    transpose_k<<<(H2 * H1 + 255) / 256, 256, 0, stream>>>(w2, w2t, H2, H1);
    transpose_k<<<(NOUT * H2 + 255) / 256, 256, 0, stream>>>(w3, w3t, NOUT, H2);

    // W -> bf16 (tiny); A converts in-GEMM
    int nw = H1 * (KP / 8);
    cvt_pad_bf16<<<(nw + 255) / 256, 256, 0, stream>>>(w1, w1b, H1, NIN, KP);

    dim3 gg(H1 / 128, M / 128);   // (4, 150) = 600 blocks (swizzle assumes 600)
    gemm_bf16_fa<<<gg, 256, 0, stream>>>(x, w1b, I1ff);

    snn_scan_wave<<<B_, 64, 0, stream>>>(I1ff, wrt, w2t, w3t,
                                         alpha1, rho1, beta_a1,
                                         alpha2, rho2, beta_a2,
                                         beta_out, out);
}